// Round 3
// baseline (371.189 us; speedup 1.0000x reference)
//
#include <hip/hip_runtime.h>

#define BUCKETS_LOG2 22
#define BUCKET_MASK ((1u << BUCKETS_LOG2) - 1u)
#define BLOCK 256

typedef float f32x4 __attribute__((ext_vector_type(4)));

__global__ __launch_bounds__(BLOCK) void hash_trilerp_kernel(
    const float* __restrict__ pts,          // (N,3)
    const float* __restrict__ vf,           // (BUCKETS, 8)
    const unsigned int* __restrict__ primes,// (3,)
    float* __restrict__ out,                // (N,8)
    int n)
{
    __shared__ float sp[3 * BLOCK];

    const int tid = threadIdx.x;
    const int i = blockIdx.x * BLOCK + tid;

    // Coalesced staging of pts (AoS stride-3) through LDS
    {
        const int base = blockIdx.x * BLOCK * 3;
        const int total = n * 3;
        #pragma unroll
        for (int k = 0; k < 3; ++k) {
            int idx = base + k * BLOCK + tid;
            if (idx < total) sp[k * BLOCK + tid] = pts[idx];
        }
    }
    __syncthreads();

    if (i >= n) return;

    const unsigned int p0 = primes[0];
    const unsigned int p1 = primes[1];
    const unsigned int p2 = primes[2];

    const float px = sp[3 * tid + 0];
    const float py = sp[3 * tid + 1];
    const float pz = sp[3 * tid + 2];

    // q = pts / RES, RES = 1/1024 (exact power of two -> multiply is exact)
    const float qx = px * 1024.0f;
    const float qy = py * 1024.0f;
    const float qz = pz * 1024.0f;

    const float bxf = floorf(qx);
    const float byf = floorf(qy);
    const float bzf = floorf(qz);
    const float fx = qx - bxf, fy = qy - byf, fz = qz - bzf;

    const unsigned int bx = (unsigned int)(int)bxf;
    const unsigned int by = (unsigned int)(int)byf;
    const unsigned int bz = (unsigned int)(int)bzf;

    // hash partials (uint32 wraparound semantics, matches reference)
    unsigned int hx[2], hy[2], hz[2];
    hx[0] = bx * p0; hx[1] = hx[0] + p0;
    hy[0] = by * p1; hy[1] = hy[0] + p1;
    hz[0] = bz * p2; hz[1] = hz[0] + p2;

    const f32x4* __restrict__ v4 = (const f32x4*)vf;

    // ---- Phase 1: compute all 8 bucket offsets ----
    size_t off[8];
    #pragma unroll
    for (int c = 0; c < 8; ++c) {
        const int cx = c & 1, cy = (c >> 1) & 1, cz = (c >> 2) & 1;
        const unsigned int vid = (hx[cx] + hy[cy] + hz[cz]) & BUCKET_MASK;
        off[c] = (size_t)vid * 2u;
    }

    // ---- Phase 2: issue ALL 16 float4 loads (maximize loads in flight) ----
    f32x4 f[16];
    #pragma unroll
    for (int c = 0; c < 8; ++c) {
        f[2 * c]     = v4[off[c]];
        f[2 * c + 1] = v4[off[c] + 1];
    }

    // ---- Phase 3: trilinear weights + accumulate ----
    const float wx[2] = { 1.0f - fx, fx };
    const float wy[2] = { 1.0f - fy, fy };
    const float wz[2] = { 1.0f - fz, fz };

    f32x4 a0 = { 0.f, 0.f, 0.f, 0.f };
    f32x4 a1 = { 0.f, 0.f, 0.f, 0.f };

    #pragma unroll
    for (int c = 0; c < 8; ++c) {
        const int cx = c & 1, cy = (c >> 1) & 1, cz = (c >> 2) & 1;
        const float w = wx[cx] * wy[cy] * wz[cz];
        a0 += w * f[2 * c];
        a1 += w * f[2 * c + 1];
    }

    // Streaming (nontemporal) store: out has no reuse
    f32x4* __restrict__ o4 = (f32x4*)out;
    __builtin_nontemporal_store(a0, &o4[(size_t)i * 2u]);
    __builtin_nontemporal_store(a1, &o4[(size_t)i * 2u + 1u]);
}

extern "C" void kernel_launch(void* const* d_in, const int* in_sizes, int n_in,
                              void* d_out, int out_size, void* d_ws, size_t ws_size,
                              hipStream_t stream) {
    const float* pts            = (const float*)d_in[0];
    const float* vf             = (const float*)d_in[1];
    const unsigned int* primes  = (const unsigned int*)d_in[2];
    float* out                  = (float*)d_out;

    const int n = in_sizes[0] / 3;   // N_PTS
    const int grid = (n + BLOCK - 1) / BLOCK;
    hash_trilerp_kernel<<<grid, BLOCK, 0, stream>>>(pts, vf, primes, out, n);
}

// Round 4
// 369.552 us; speedup vs baseline: 1.0044x; 1.0044x over previous
//
#include <hip/hip_runtime.h>

#define BUCKETS_LOG2 22
#define BUCKET_MASK ((1u << BUCKETS_LOG2) - 1u)
#define BLOCK 256

typedef float f32x4 __attribute__((ext_vector_type(4)));

__global__ __launch_bounds__(BLOCK) void hash_trilerp_kernel(
    const float* __restrict__ pts,          // (N,3)
    const float* __restrict__ vf,           // (BUCKETS, 8)
    const unsigned int* __restrict__ primes,// (3,)
    float* __restrict__ out,                // (N,8)
    int n)
{
    __shared__ float sp[3 * BLOCK];

    const int tid = threadIdx.x;
    const int i = blockIdx.x * BLOCK + tid;

    // Coalesced staging of pts (AoS stride-3) through LDS
    {
        const int base = blockIdx.x * BLOCK * 3;
        const int total = n * 3;
        #pragma unroll
        for (int k = 0; k < 3; ++k) {
            int idx = base + k * BLOCK + tid;
            if (idx < total) sp[k * BLOCK + tid] = pts[idx];
        }
    }
    __syncthreads();

    if (i >= n) return;

    const unsigned int p0 = primes[0];
    const unsigned int p1 = primes[1];
    const unsigned int p2 = primes[2];

    const float px = sp[3 * tid + 0];
    const float py = sp[3 * tid + 1];
    const float pz = sp[3 * tid + 2];

    // q = pts / RES, RES = 1/1024 (exact power of two -> multiply is exact)
    const float qx = px * 1024.0f;
    const float qy = py * 1024.0f;
    const float qz = pz * 1024.0f;

    const float bxf = floorf(qx);
    const float byf = floorf(qy);
    const float bzf = floorf(qz);
    const float fx = qx - bxf, fy = qy - byf, fz = qz - bzf;

    const unsigned int bx = (unsigned int)(int)bxf;
    const unsigned int by = (unsigned int)(int)byf;
    const unsigned int bz = (unsigned int)(int)bzf;

    // hash partials (uint32 wraparound semantics, matches reference)
    unsigned int hx[2], hy[2], hz[2];
    hx[0] = bx * p0; hx[1] = hx[0] + p0;
    hy[0] = by * p1; hy[1] = hy[0] + p1;
    hz[0] = bz * p2; hz[1] = hz[0] + p2;

    const char* __restrict__ vfb = (const char*)vf;

    // ---- Phase 1: all 8 bucket BYTE offsets as uint32 (table = 128 MB < 2^32,
    //      enables SADDR-form global_load: 1 VGPR per address) ----
    unsigned int boff[8];
    #pragma unroll
    for (int c = 0; c < 8; ++c) {
        const int cx = c & 1, cy = (c >> 1) & 1, cz = (c >> 2) & 1;
        const unsigned int vid = (hx[cx] + hy[cy] + hz[cz]) & BUCKET_MASK;
        boff[c] = vid << 5;   // * 32 bytes per bucket
    }

    // ---- Phase 2: issue ALL 16 float4 loads; sched_barrier(0) pins them
    //      BEFORE any consumption so all 16 stay in flight (MLP) ----
    f32x4 f[16];
    #pragma unroll
    for (int c = 0; c < 8; ++c) {
        f[2 * c]     = *(const f32x4*)(vfb + boff[c]);
        f[2 * c + 1] = *(const f32x4*)(vfb + boff[c] + 16);
    }
    __builtin_amdgcn_sched_barrier(0);

    // ---- Phase 3: trilinear weights + accumulate ----
    const float wx[2] = { 1.0f - fx, fx };
    const float wy[2] = { 1.0f - fy, fy };
    const float wz[2] = { 1.0f - fz, fz };

    f32x4 a0 = { 0.f, 0.f, 0.f, 0.f };
    f32x4 a1 = { 0.f, 0.f, 0.f, 0.f };

    #pragma unroll
    for (int c = 0; c < 8; ++c) {
        const int cx = c & 1, cy = (c >> 1) & 1, cz = (c >> 2) & 1;
        const float w = wx[cx] * wy[cy] * wz[cz];
        a0 += w * f[2 * c];
        a1 += w * f[2 * c + 1];
    }

    // Streaming (nontemporal) store: out has no reuse
    f32x4* __restrict__ o4 = (f32x4*)out;
    __builtin_nontemporal_store(a0, &o4[(size_t)i * 2u]);
    __builtin_nontemporal_store(a1, &o4[(size_t)i * 2u + 1u]);
}

extern "C" void kernel_launch(void* const* d_in, const int* in_sizes, int n_in,
                              void* d_out, int out_size, void* d_ws, size_t ws_size,
                              hipStream_t stream) {
    const float* pts            = (const float*)d_in[0];
    const float* vf             = (const float*)d_in[1];
    const unsigned int* primes  = (const unsigned int*)d_in[2];
    float* out                  = (float*)d_out;

    const int n = in_sizes[0] / 3;   // N_PTS
    const int grid = (n + BLOCK - 1) / BLOCK;
    hash_trilerp_kernel<<<grid, BLOCK, 0, stream>>>(pts, vf, primes, out, n);
}

// Round 5
// 368.262 us; speedup vs baseline: 1.0079x; 1.0035x over previous
//
#include <hip/hip_runtime.h>

#define BUCKETS_LOG2 22
#define BUCKET_MASK ((1u << BUCKETS_LOG2) - 1u)
#define BLOCK 256

typedef float f32x4 __attribute__((ext_vector_type(4)));

__global__ __launch_bounds__(BLOCK) void hash_trilerp_kernel(
    const float* __restrict__ pts,          // (N,3)
    const float* __restrict__ vf,           // (BUCKETS, 8)
    const unsigned int* __restrict__ primes,// (3,)
    float* __restrict__ out,                // (N,8)
    int n)
{
    __shared__ float sp[3 * BLOCK];

    const int tid = threadIdx.x;
    const int i = blockIdx.x * BLOCK + tid;

    // Coalesced staging of pts (AoS stride-3) through LDS
    {
        const int base = blockIdx.x * BLOCK * 3;
        const int total = n * 3;
        #pragma unroll
        for (int k = 0; k < 3; ++k) {
            int idx = base + k * BLOCK + tid;
            if (idx < total) sp[k * BLOCK + tid] = pts[idx];
        }
    }
    __syncthreads();

    if (i >= n) return;

    const unsigned int p0 = primes[0];
    const unsigned int p1 = primes[1];
    const unsigned int p2 = primes[2];

    const float px = sp[3 * tid + 0];
    const float py = sp[3 * tid + 1];
    const float pz = sp[3 * tid + 2];

    // q = pts / RES, RES = 1/1024 (exact power of two -> multiply is exact)
    const float qx = px * 1024.0f;
    const float qy = py * 1024.0f;
    const float qz = pz * 1024.0f;

    const float bxf = floorf(qx);
    const float byf = floorf(qy);
    const float bzf = floorf(qz);
    const float fx = qx - bxf, fy = qy - byf, fz = qz - bzf;

    const unsigned int bx = (unsigned int)(int)bxf;
    const unsigned int by = (unsigned int)(int)byf;
    const unsigned int bz = (unsigned int)(int)bzf;

    // hash partials (uint32 wraparound semantics, matches reference)
    unsigned int hx[2], hy[2], hz[2];
    hx[0] = bx * p0; hx[1] = hx[0] + p0;
    hy[0] = by * p1; hy[1] = hy[0] + p1;
    hz[0] = bz * p2; hz[1] = hz[0] + p2;

    // ---- Phase 1: all 8 bucket BYTE offsets as uint32 (table = 128 MB < 2^32) ----
    unsigned int boff[8];
    #pragma unroll
    for (int c = 0; c < 8; ++c) {
        const int cx = c & 1, cy = (c >> 1) & 1, cz = (c >> 2) & 1;
        const unsigned int vid = (hx[cx] + hy[cy] + hz[cz]) & BUCKET_MASK;
        boff[c] = vid << 5;   // * 32 bytes per bucket
    }

    // ---- Phase 2: force ALL 16 dwordx4 loads into flight via inline asm
    //      (saddr form: SGPR base + uint32 voffset), then ONE vmcnt(0). ----
    f32x4 f0, f1, f2, f3, f4, f5, f6, f7, f8, f9, f10, f11, f12, f13, f14, f15;
    #define GLD(dst, off, imm) \
        asm volatile("global_load_dwordx4 %0, %1, %2 offset:" #imm \
                     : "=v"(dst) : "v"(off), "s"(vf))
    GLD(f0,  boff[0], 0);  GLD(f1,  boff[0], 16);
    GLD(f2,  boff[1], 0);  GLD(f3,  boff[1], 16);
    GLD(f4,  boff[2], 0);  GLD(f5,  boff[2], 16);
    GLD(f6,  boff[3], 0);  GLD(f7,  boff[3], 16);
    GLD(f8,  boff[4], 0);  GLD(f9,  boff[4], 16);
    GLD(f10, boff[5], 0);  GLD(f11, boff[5], 16);
    GLD(f12, boff[6], 0);  GLD(f13, boff[6], 16);
    GLD(f14, boff[7], 0);  GLD(f15, boff[7], 16);
    #undef GLD

    // Single drain; "+v" ties force every consumer below this point.
    asm volatile("s_waitcnt vmcnt(0)"
                 : "+v"(f0), "+v"(f1), "+v"(f2), "+v"(f3),
                   "+v"(f4), "+v"(f5), "+v"(f6), "+v"(f7),
                   "+v"(f8), "+v"(f9), "+v"(f10), "+v"(f11),
                   "+v"(f12), "+v"(f13), "+v"(f14), "+v"(f15)
                 :: "memory");

    // ---- Phase 3: trilinear weights + accumulate ----
    const float wx[2] = { 1.0f - fx, fx };
    const float wy[2] = { 1.0f - fy, fy };
    const float wz[2] = { 1.0f - fz, fz };

    float w[8];
    #pragma unroll
    for (int c = 0; c < 8; ++c) {
        const int cx = c & 1, cy = (c >> 1) & 1, cz = (c >> 2) & 1;
        w[c] = wx[cx] * wy[cy] * wz[cz];
    }

    f32x4 a0 = { 0.f, 0.f, 0.f, 0.f };
    f32x4 a1 = { 0.f, 0.f, 0.f, 0.f };
    a0 += w[0] * f0;  a1 += w[0] * f1;
    a0 += w[1] * f2;  a1 += w[1] * f3;
    a0 += w[2] * f4;  a1 += w[2] * f5;
    a0 += w[3] * f6;  a1 += w[3] * f7;
    a0 += w[4] * f8;  a1 += w[4] * f9;
    a0 += w[5] * f10; a1 += w[5] * f11;
    a0 += w[6] * f12; a1 += w[6] * f13;
    a0 += w[7] * f14; a1 += w[7] * f15;

    // Streaming (nontemporal) store: out has no reuse
    f32x4* __restrict__ o4 = (f32x4*)out;
    __builtin_nontemporal_store(a0, &o4[(size_t)i * 2u]);
    __builtin_nontemporal_store(a1, &o4[(size_t)i * 2u + 1u]);
}

extern "C" void kernel_launch(void* const* d_in, const int* in_sizes, int n_in,
                              void* d_out, int out_size, void* d_ws, size_t ws_size,
                              hipStream_t stream) {
    const float* pts            = (const float*)d_in[0];
    const float* vf             = (const float*)d_in[1];
    const unsigned int* primes  = (const unsigned int*)d_in[2];
    float* out                  = (float*)d_out;

    const int n = in_sizes[0] / 3;   // N_PTS
    const int grid = (n + BLOCK - 1) / BLOCK;
    hash_trilerp_kernel<<<grid, BLOCK, 0, stream>>>(pts, vf, primes, out, n);
}